// Round 14
// baseline (141.802 us; speedup 1.0000x reference)
//
#include <hip/hip_runtime.h>

typedef unsigned short u16;
typedef unsigned long long u64;
typedef __attribute__((ext_vector_type(8))) short short8;   // bf16x8 MFMA fragment
typedef __attribute__((ext_vector_type(4))) float f32x4;

#define MFMA16(A,B,C) __builtin_amdgcn_mfma_f32_16x16x32_bf16(A,B,C,0,0,0)
#define NEG_INF_F (-4294967295.0f)

#define Bsz 8
#define Lsz 2048
#define Dsz 128

__device__ __forceinline__ u16 f2bf(float f){
  union { float f; unsigned u; } v; v.f = f;
  unsigned u = v.u;
  return (u16)((u + 0x7fffu + ((u >> 16) & 1u)) >> 16);
}
__device__ __forceinline__ float bf2f(u16 h){
  union { float f; unsigned u; } v; v.u = ((unsigned)h) << 16;
  return v.f;
}

// ---------------- W -> bf16 pre-conversion (once) ---------------------------
__global__ __launch_bounds__(256) void wconv_kernel(
    const float* __restrict__ Wq, const float* __restrict__ Wk,
    const float* __restrict__ Wv, u16* __restrict__ wb)
{
  int i = blockIdx.x * 256 + threadIdx.x;     // grid 192 -> 49152
  if (i < 16384) wb[i] = f2bf(Wq[i]);
  else if (i < 32768) wb[i] = f2bf(Wk[i - 16384]);
  else if (i < 49152) wb[i] = f2bf(Wv[i - 32768]);
}

// ---------------- projection: y = x @ W^T + b, Lorentz map -----------------
#define LPX 136   // bf16 pitch
#define LPY 133   // f32 pitch

__global__ __launch_bounds__(256) void proj_kernel(
    const float* __restrict__ xq, const float* __restrict__ xk, const float* __restrict__ xv,
    const u16* __restrict__ wb,
    const float* __restrict__ bq, const float* __restrict__ bk, const float* __restrict__ bv,
    const float* __restrict__ sq, const float* __restrict__ sk, const float* __restrict__ sv,
    const float* __restrict__ attn_scale,
    u16* __restrict__ qout, u16* __restrict__ kout,
    u16* __restrict__ vthi, u16* __restrict__ vtlo,
    float* __restrict__ tqo, float* __restrict__ tko,
    float* __restrict__ vpart)
{
  const int z = blockIdx.z;
  const float* x  = (z == 0) ? xq : (z == 1) ? xk : xv;
  const u16*   Wb = wb + z * 16384;
  const float* bb = (z == 0) ? bq : (z == 1) ? bk : bv;
  const float* ss = (z == 0) ? sq : (z == 1) ? sk : sv;

  __shared__ u16  xl[64 * LPX];
  __shared__ u16  wl[128 * LPX];
  __shared__ float yl[64 * LPY];
  __shared__ float scl[64];
  __shared__ float tml[64];

  const int t = threadIdx.x;
  const long row0 = (long)blockIdx.x * 64;

  for (int i = t; i < 2048; i += 256) {       // W bf16, 16B chunks
    int r = i >> 4, c8 = (i & 15) * 8;
    *(short8*)&wl[r * LPX + c8] = *(const short8*)&Wb[r * 128 + c8];
  }
  for (int i = t; i < 2048; i += 256) {       // x f32 -> bf16, 4 at a time
    int off = i * 4;
    int r = off >> 7, c = off & 127;
    f32x4 xv4 = *(const f32x4*)(x + row0 * 128 + off);
    u64 wv = (u64)f2bf(xv4[0]) | ((u64)f2bf(xv4[1]) << 16)
           | ((u64)f2bf(xv4[2]) << 32) | ((u64)f2bf(xv4[3]) << 48);
    *(u64*)&xl[r * LPX + c] = wv;
  }
  __syncthreads();

  const int l = t & 63, wid = t >> 6;
  const int qr = l & 15, g = l >> 4;
  const int r0 = wid * 16;

  short8 af[4];
#pragma unroll
  for (int ks = 0; ks < 4; ks++)
    af[ks] = *(const short8*)&xl[(r0 + qr) * LPX + ks * 32 + g * 8];

  f32x4 acc[8];
#pragma unroll
  for (int jt = 0; jt < 8; jt++) acc[jt] = (f32x4){0.f, 0.f, 0.f, 0.f};

#pragma unroll
  for (int ks = 0; ks < 4; ks++) {
#pragma unroll
    for (int jt = 0; jt < 8; jt++) {
      short8 bfr = *(const short8*)&wl[(jt * 16 + qr) * LPX + ks * 32 + g * 8];
      acc[jt] = MFMA16(af[ks], bfr, acc[jt]);
    }
  }

  float bbv[8];
#pragma unroll
  for (int jt = 0; jt < 8; jt++) bbv[jt] = bb[jt * 16 + qr];

  float ssq[4] = {0.f, 0.f, 0.f, 0.f};
#pragma unroll
  for (int jt = 0; jt < 8; jt++)
#pragma unroll
    for (int r = 0; r < 4; r++) {
      float yv = acc[jt][r] + bbv[jt];
      acc[jt][r] = yv;
      float s2 = yv * yv;
      if (jt == 0) s2 = (qr == 0) ? 0.f : s2;   // exclude d=0
      ssq[r] += s2;
    }
#pragma unroll
  for (int r = 0; r < 4; r++) {
    ssq[r] += __shfl_xor(ssq[r], 1);
    ssq[r] += __shfl_xor(ssq[r], 2);
    ssq[r] += __shfl_xor(ssq[r], 4);
    ssq[r] += __shfl_xor(ssq[r], 8);
  }

  const float es = __expf(ss[0]);
  const float fold = 2.0f / attn_scale[0];

  float tvv[4], sclv[4];
#pragma unroll
  for (int r = 0; r < 4; r++) {
    float y0 = __shfl(acc[0][r], l & 48);     // qr==0 lane of same g: d=0 value
    float tv = es / (1.0f + __expf(-y0)) + 1.1f;
    tvv[r] = tv;
    sclv[r] = sqrtf((tv * tv - 1.0f) / ssq[r]);
  }
  if (qr == 0) {
#pragma unroll
    for (int r = 0; r < 4; r++) {
      tml[r0 + g * 4 + r] = tvv[r];
      scl[r0 + g * 4 + r] = sclv[r];
    }
  }
#pragma unroll
  for (int jt = 0; jt < 8; jt++)
#pragma unroll
    for (int r = 0; r < 4; r++)
      yl[(r0 + g * 4 + r) * LPY + jt * 16 + qr] = acc[jt][r];
  __syncthreads();

  const long gbase = row0 * 128;
  if (z == 0) {
    for (int i = t; i < 64 * 128; i += 256) {
      int r = i >> 7, d = i & 127;
      float v = (d == 0) ? 0.f : yl[r * LPY + d] * scl[r] * fold;
      qout[gbase + i] = f2bf(v);
    }
    if (t < 64) tqo[row0 + t] = -tml[t] * fold;
  } else if (z == 1) {
    for (int i = t; i < 64 * 128; i += 256) {
      int r = i >> 7, d = i & 127;
      float v = (d == 0) ? 0.f : yl[r * LPY + d] * scl[r];
      kout[gbase + i] = f2bf(v);
    }
    if (t < 64) tko[row0 + t] = tml[t];
  } else {
    const int b = (int)(row0 >> 11);
    const int lpos = (int)(row0 & 2047);
    for (int i = t; i < 128 * 64; i += 256) {
      int d = i >> 6, r = i & 63;
      float v = (d == 0) ? tml[r] : yl[r * LPY + d] * scl[r];
      u16 hi = f2bf(v);
      float lo = v - bf2f(hi);
      long idx = ((long)(b * 128 + d)) * 2048 + lpos + r;
      vthi[idx] = hi;
      vtlo[idx] = f2bf(lo);
    }
    if (t < 128) {
      float s = 0.f;
      for (int r = 0; r < 64; r++)
        s += (t == 0) ? tml[r] : yl[r * LPY + t] * scl[r];
      int blk = (int)((row0 >> 6) & 31);
      vpart[((long)(b * 32 + blk)) * 128 + t] = s;
    }
  }
}

// ---------------- pack key-padding mask: one wave per 64-bit word -----------
__global__ __launch_bounds__(256) void pack_mask_kernel(
    const int* __restrict__ mask, u64* __restrict__ pmask)
{
  int gt = blockIdx.x * 256 + threadIdx.x;
  int w = gt >> 6;
  int lane = gt & 63;
  if (w >= Bsz * 32) return;
  u64 word = __ballot(mask[w * 64 + lane] != 0);
  if (lane == 0) pmask[w] = word;
}

// ---------------- deterministic v-sum reduce --------------------------------
__global__ __launch_bounds__(128) void vreduce_kernel(
    const float* __restrict__ vpart, float* __restrict__ vsum)
{
  int i = blockIdx.x * 128 + threadIdx.x;
  int b = i >> 7, d = i & 127;
  float s = 0.f;
  for (int j = 0; j < 32; j++) s += vpart[((long)(b * 32 + j)) * 128 + d];
  vsum[i] = s;
}

// ---------------- flash attention + Lorentz epilogue ------------------------
// FIXED-SHIFT softmax: logits provably <= MS-1 (rows normalized by
// construction, time term < 0), so p = exp(val - MS) needs NO running max,
// NO rescale, NO stat exchange -> ONE barrier/tile. Block = 512 thr = 8 waves
// on a 32-q-row strip: wave w owns keys [16w,+16) (K rows unique/wave) and
// d in [16w,+16) (V rows unique/wave) -> K,V fully register-resident,
// prefetched one tile ahead; ONLY P goes through LDS (16KB dbuf, XOR-swizzle).
// Barrier = raw lgkmcnt(0)+s_barrier (global prefetches stay in flight, T4).
// Grid 512 longest-first = 2 blocks/CU + LPT refill. b = blk&7 (XCD pin).
__global__ __launch_bounds__(512, 4) void flash_kernel(
    const u16* __restrict__ qbf, const u16* __restrict__ kb,
    const u16* __restrict__ vthi, const u16* __restrict__ vtlo,
    const float* __restrict__ tq, const float* __restrict__ tk,
    const u64* __restrict__ pmask, const float* __restrict__ vsum,
    const float* __restrict__ sqp, const float* __restrict__ skp,
    const float* __restrict__ asp,
    float* __restrict__ out)
{
  __shared__ u16 Pl[2][32 * 128];       // 16 KB, XOR-swizzled (chunk ^= row&7)
  __shared__ float lLd[8][2][16];
  __shared__ float ssqw[8][2][16];

  const int t = threadIdx.x;
  const int w = t >> 6, l = t & 63;
  const int qr = l & 15, g = l >> 4;
  const int blk = blockIdx.x;
  const int b = blk & 7;                // batch == XCD (round-robin dispatch)
  const int s = 63 - (blk >> 3);        // 32-row strip, longest first
  const int qbase = s * 32;
  const int nkt = (qbase + 159) >> 7;   // 128-key tiles covering [0, qbase+32)

  // data-independent logit bound -> fixed softmax shift
  const float fold = 2.0f / asp[0];
  const float tqm = __expf(sqp[0]) + 1.1f;
  const float tkm = __expf(skp[0]) + 1.1f;
  const float MS = fold * sqrtf((tqm * tqm - 1.f) * (tkm * tkm - 1.f)) + 1.0f;

  short8 qf[2][4];
  float tqv0, tqv1;
  {
    const u16* qp0 = qbf + ((long)(b * 2048 + qbase + qr)) * 128 + g * 8;
    const u16* qp1 = qp0 + 16 * 128;
#pragma unroll
    for (int ks = 0; ks < 4; ks++) {
      qf[0][ks] = *(const short8*)(qp0 + ks * 32);
      qf[1][ks] = *(const short8*)(qp1 + ks * 32);
    }
    tqv0 = tq[b * 2048 + qbase + qr];
    tqv1 = tq[b * 2048 + qbase + 16 + qr];
  }

  const u16* kbase  = kb   + ((long)(b * 2048 + 16 * w + qr)) * 128 + g * 8;
  const u16* vhbase = vthi + ((long)(b * 128 + 16 * w + qr)) * 2048 + g * 8;
  const u16* vlbase = vtlo + ((long)(b * 128 + 16 * w + qr)) * 2048 + g * 8;

  float lsum0 = 0.f, lsum1 = 0.f;
  f32x4 acc0 = (f32x4){0.f, 0.f, 0.f, 0.f};
  f32x4 acc1 = (f32x4){0.f, 0.f, 0.f, 0.f};

  short8 kc[4], vh[4], vl[4];
#pragma unroll
  for (int ks = 0; ks < 4; ks++) kc[ks] = *(const short8*)(kbase + ks * 32);
  f32x4 tkvc = *(const f32x4*)(tk + b * 2048 + 16 * w + g * 4);
  u64 mwc = pmask[b * 32 + (w >> 2)];

  int cur = 0;
  for (int kt = 0; kt < nkt; kt++) {
    const long k0 = (long)kt << 7;

    // ---- QK(kt) from registers ----
    f32x4 sv0 = (f32x4){0.f, 0.f, 0.f, 0.f};
    f32x4 sv1 = (f32x4){0.f, 0.f, 0.f, 0.f};
#pragma unroll
    for (int ks = 0; ks < 4; ks++) {
      sv0 = MFMA16(kc[ks], qf[0][ks], sv0);
      sv1 = MFMA16(kc[ks], qf[1][ks], sv1);
    }
    // prefetch K(kt+1) into the same regs (rotation)
    if (kt + 1 < nkt) {
      const u16* kp = kbase + (k0 + 128) * 128;
#pragma unroll
      for (int ks = 0; ks < 4; ks++) kc[ks] = *(const short8*)(kp + ks * 32);
    }

    // ---- fixed-shift softmax (no max, no rescale) ----
    const bool bndry = (k0 + 127 > qbase);
    float p0[4], p1[4];
#pragma unroll
    for (int r = 0; r < 4; r++) {
      int kl = 16 * w + 4 * g + r;
      bool bad = ((mwc >> (kl & 63)) & 1ull) != 0ull;
      bool bad0 = bad, bad1 = bad;
      if (bndry) {
        bad0 |= (k0 + kl > qbase + qr);
        bad1 |= (k0 + kl > qbase + 16 + qr);
      }
      float e0 = __expf(sv0[r] + tqv0 * tkvc[r] - MS);
      float e1 = __expf(sv1[r] + tqv1 * tkvc[r] - MS);
      p0[r] = bad0 ? 0.f : e0;
      p1[r] = bad1 ? 0.f : e1;
      lsum0 += p0[r];
      lsum1 += p1[r];
    }
    // P -> LDS (swizzled)
    {
      int pch = ((2 * w + (g >> 1)) ^ (qr & 7)) * 8 + (g & 1) * 4;
      u64 w0 = (u64)f2bf(p0[0]) | ((u64)f2bf(p0[1]) << 16)
             | ((u64)f2bf(p0[2]) << 32) | ((u64)f2bf(p0[3]) << 48);
      u64 w1 = (u64)f2bf(p1[0]) | ((u64)f2bf(p1[1]) << 16)
             | ((u64)f2bf(p1[2]) << 32) | ((u64)f2bf(p1[3]) << 48);
      *(u64*)&Pl[cur][qr * 128 + pch] = w0;
      *(u64*)&Pl[cur][(16 + qr) * 128 + pch] = w1;
    }
    // prefetch tkv/mask for kt+1
    if (kt + 1 < nkt) {
      tkvc = *(const f32x4*)(tk + b * 2048 + k0 + 128 + 16 * w + g * 4);
      mwc = pmask[b * 32 + (int)(k0 >> 6) + 2 + (w >> 2)];
    }

    // ---- PV(kt-1): P from LDS (prev buffer), V from registers ----
    if (kt > 0) {
      const u16* Pb = &Pl[cur ^ 1][0];
#pragma unroll
      for (int ks = 0; ks < 4; ks++) {
        int ch = ((4 * ks + g) ^ (qr & 7)) * 8;
        short8 pf0 = *(const short8*)&Pb[qr * 128 + ch];
        short8 pf1 = *(const short8*)&Pb[(16 + qr) * 128 + ch];
        acc0 = MFMA16(vh[ks], pf0, acc0);
        acc0 = MFMA16(vl[ks], pf0, acc0);
        acc1 = MFMA16(vh[ks], pf1, acc1);
        acc1 = MFMA16(vl[ks], pf1, acc1);
      }
    }

    // ---- issue V(kt) loads (consumed next interval / final PV) ----
#pragma unroll
    for (int ks = 0; ks < 4; ks++) {
      vh[ks] = *(const short8*)(vhbase + k0 + ks * 32);
      vl[ks] = *(const short8*)(vlbase + k0 + ks * 32);
    }

    // single barrier: drain LDS writes only; global loads stay in flight
    asm volatile("s_waitcnt lgkmcnt(0)\n\ts_barrier" ::: "memory");
    cur ^= 1;
  }

  // ---- final PV(nkt-1) ----
  {
    const u16* Pb = &Pl[cur ^ 1][0];
#pragma unroll
    for (int ks = 0; ks < 4; ks++) {
      int ch = ((4 * ks + g) ^ (qr & 7)) * 8;
      short8 pf0 = *(const short8*)&Pb[qr * 128 + ch];
      short8 pf1 = *(const short8*)&Pb[(16 + qr) * 128 + ch];
      acc0 = MFMA16(vh[ks], pf0, acc0);
      acc0 = MFMA16(vl[ks], pf0, acc0);
      acc1 = MFMA16(vh[ks], pf1, acc1);
      acc1 = MFMA16(vl[ks], pf1, acc1);
    }
  }

  // ---- epilogue: lsum reduce (once, not per tile) + Lorentz normalize ----
  lsum0 += __shfl_xor(lsum0, 16); lsum0 += __shfl_xor(lsum0, 32);
  lsum1 += __shfl_xor(lsum1, 16); lsum1 += __shfl_xor(lsum1, 32);
  if (g == 0) { lLd[w][0][qr] = lsum0; lLd[w][1][qr] = lsum1; }
  __syncthreads();

  float Lt0 = 0.f, Lt1 = 0.f;
#pragma unroll
  for (int j = 0; j < 8; j++) { Lt0 += lLd[j][0][qr]; Lt1 += lLd[j][1][qr]; }
  const bool mrow0 = (Lt0 == 0.f);      // fully masked -> uniform over ALL keys
  const bool mrow1 = (Lt1 == 0.f);
  const float invL0 = mrow0 ? 0.f : 1.0f / Lt0;
  const float invL1 = mrow1 ? 0.f : 1.0f / Lt1;

  const float* vs = vsum + b * 128;
  float av0[4], av1[4];
  float pp0 = 0.f, pp1 = 0.f;
#pragma unroll
  for (int r = 0; r < 4; r++) {
    int d = 16 * w + 4 * g + r;
    float u = vs[d] * (1.0f / 2048.0f);
    float a0 = mrow0 ? u : acc0[r] * invL0;
    float a1 = mrow1 ? u : acc1[r] * invL1;
    av0[r] = a0; av1[r] = a1;
    float sgn = (d == 0) ? -1.f : 1.f;
    pp0 += sgn * a0 * a0;
    pp1 += sgn * a1 * a1;
  }
  pp0 += __shfl_xor(pp0, 16); pp0 += __shfl_xor(pp0, 32);
  pp1 += __shfl_xor(pp1, 16); pp1 += __shfl_xor(pp1, 32);
  if (g == 0) { ssqw[w][0][qr] = pp0; ssqw[w][1][qr] = pp1; }
  __syncthreads();

  float lor0 = 0.f, lor1 = 0.f;
#pragma unroll
  for (int j = 0; j < 8; j++) { lor0 += ssqw[j][0][qr]; lor1 += ssqw[j][1][qr]; }
  float rd0 = 1.0f / sqrtf(fmaxf(fabsf(lor0), 1e-8f));
  float rd1 = 1.0f / sqrtf(fmaxf(fabsf(lor1), 1e-8f));

  float* op0 = out + ((long)(b * 2048 + qbase + qr)) * 128 + 16 * w + 4 * g;
  float* op1 = out + ((long)(b * 2048 + qbase + 16 + qr)) * 128 + 16 * w + 4 * g;
  f32x4 o0, o1;
  o0[0] = av0[0] * rd0; o0[1] = av0[1] * rd0; o0[2] = av0[2] * rd0; o0[3] = av0[3] * rd0;
  o1[0] = av1[0] * rd1; o1[1] = av1[1] * rd1; o1[2] = av1[2] * rd1; o1[3] = av1[3] * rd1;
  *(f32x4*)op0 = o0;
  *(f32x4*)op1 = o1;
}

// ---------------- launch ----------------------------------------------------
extern "C" void kernel_launch(void* const* d_in, const int* in_sizes, int n_in,
                              void* d_out, int out_size, void* d_ws, size_t ws_size,
                              hipStream_t stream)
{
  const float* query = (const float*)d_in[0];
  const float* key   = (const float*)d_in[1];
  const float* value = (const float*)d_in[2];
  const int*   mask  = (const int*)d_in[3];
  const float* Wq = (const float*)d_in[4];
  const float* bq = (const float*)d_in[5];
  const float* sq = (const float*)d_in[6];
  const float* Wk = (const float*)d_in[7];
  const float* bk = (const float*)d_in[8];
  const float* sk = (const float*)d_in[9];
  const float* Wv = (const float*)d_in[10];
  const float* bv = (const float*)d_in[11];
  const float* sv = (const float*)d_in[12];
  const float* attn_scale = (const float*)d_in[13];
  // d_in[14] = attn_bias: cancels in softmax, unused

  float* out = (float*)d_out;
  char* ws = (char*)d_ws;

  float* vsum  = (float*)ws;                        // 4 KB
  u64*   pmask = (u64*)(ws + 4096);                 // 2 KB (pad to 4 KB)
  float* tqa   = (float*)(ws + 8192);               // 64 KB
  float* tka   = (float*)(ws + 8192 + 65536);       // 64 KB
  float* vpart = (float*)(ws + 8192 + 131072);      // 128 KB
  u16*   wb    = (u16*)(ws + 8192 + 262144);        // 96 KB (pad to 128 KB)
  char*  big   = ws + 8192 + 262144 + 131072;
  u16*   qbuf  = (u16*)big;                         // 4 MB
  u16*   kbuf  = qbuf + (size_t)16384 * 128;        // 4 MB
  u16*   vthi  = kbuf + (size_t)16384 * 128;        // 4 MB
  u16*   vtlo  = vthi + (size_t)16384 * 128;        // 4 MB

  wconv_kernel<<<192, 256, 0, stream>>>(Wq, Wk, Wv, wb);
  proj_kernel<<<dim3(256, 1, 3), 256, 0, stream>>>(
      query, key, value, wb, bq, bk, bv, sq, sk, sv, attn_scale,
      qbuf, kbuf, vthi, vtlo, tqa, tka, vpart);
  pack_mask_kernel<<<64, 256, 0, stream>>>(mask, pmask);
  vreduce_kernel<<<8, 128, 0, stream>>>(vpart, vsum);
  flash_kernel<<<512, 512, 0, stream>>>(
      qbuf, kbuf, vthi, vtlo, tqa, tka, pmask, vsum, sq, sk, attn_scale, out);
}

// Round 15
// 101.671 us; speedup vs baseline: 1.3947x; 1.3947x over previous
//
#include <hip/hip_runtime.h>

typedef unsigned short u16;
typedef unsigned long long u64;
typedef __attribute__((ext_vector_type(8))) short short8;   // bf16x8 MFMA fragment
typedef __attribute__((ext_vector_type(4))) float f32x4;

#define MFMA16(A,B,C) __builtin_amdgcn_mfma_f32_16x16x32_bf16(A,B,C,0,0,0)
#define NEG_INF_F (-4294967295.0f)

#define Bsz 8
#define Lsz 2048
#define Dsz 128

__device__ __forceinline__ u16 f2bf(float f){
  union { float f; unsigned u; } v; v.f = f;
  unsigned u = v.u;
  return (u16)((u + 0x7fffu + ((u >> 16) & 1u)) >> 16);
}
__device__ __forceinline__ float bf2f(u16 h){
  union { float f; unsigned u; } v; v.u = ((unsigned)h) << 16;
  return v.f;
}

// ---------------- W -> bf16 pre-conversion (once) ---------------------------
__global__ __launch_bounds__(256) void wconv_kernel(
    const float* __restrict__ Wq, const float* __restrict__ Wk,
    const float* __restrict__ Wv, u16* __restrict__ wb)
{
  int i = blockIdx.x * 256 + threadIdx.x;     // grid 192 -> 49152
  if (i < 16384) wb[i] = f2bf(Wq[i]);
  else if (i < 32768) wb[i] = f2bf(Wk[i - 16384]);
  else if (i < 49152) wb[i] = f2bf(Wv[i - 32768]);
}

// ---------------- projection: y = x @ W^T + b, Lorentz map -----------------
#define LPX 136   // bf16 pitch
#define LPY 133   // f32 pitch

__global__ __launch_bounds__(256) void proj_kernel(
    const float* __restrict__ xq, const float* __restrict__ xk, const float* __restrict__ xv,
    const u16* __restrict__ wb,
    const float* __restrict__ bq, const float* __restrict__ bk, const float* __restrict__ bv,
    const float* __restrict__ sq, const float* __restrict__ sk, const float* __restrict__ sv,
    const float* __restrict__ attn_scale,
    u16* __restrict__ qout, u16* __restrict__ kout,
    u16* __restrict__ vthi, u16* __restrict__ vtlo,
    float* __restrict__ tqo, float* __restrict__ tko,
    float* __restrict__ vpart)
{
  const int z = blockIdx.z;
  const float* x  = (z == 0) ? xq : (z == 1) ? xk : xv;
  const u16*   Wb = wb + z * 16384;
  const float* bb = (z == 0) ? bq : (z == 1) ? bk : bv;
  const float* ss = (z == 0) ? sq : (z == 1) ? sk : sv;

  __shared__ u16  xl[64 * LPX];
  __shared__ u16  wl[128 * LPX];
  __shared__ float yl[64 * LPY];
  __shared__ float scl[64];
  __shared__ float tml[64];

  const int t = threadIdx.x;
  const long row0 = (long)blockIdx.x * 64;

  for (int i = t; i < 2048; i += 256) {       // W bf16, 16B chunks
    int r = i >> 4, c8 = (i & 15) * 8;
    *(short8*)&wl[r * LPX + c8] = *(const short8*)&Wb[r * 128 + c8];
  }
  for (int i = t; i < 2048; i += 256) {       // x f32 -> bf16, 4 at a time
    int off = i * 4;
    int r = off >> 7, c = off & 127;
    f32x4 xv4 = *(const f32x4*)(x + row0 * 128 + off);
    u64 wv = (u64)f2bf(xv4[0]) | ((u64)f2bf(xv4[1]) << 16)
           | ((u64)f2bf(xv4[2]) << 32) | ((u64)f2bf(xv4[3]) << 48);
    *(u64*)&xl[r * LPX + c] = wv;
  }
  __syncthreads();

  const int l = t & 63, wid = t >> 6;
  const int qr = l & 15, g = l >> 4;
  const int r0 = wid * 16;

  short8 af[4];
#pragma unroll
  for (int ks = 0; ks < 4; ks++)
    af[ks] = *(const short8*)&xl[(r0 + qr) * LPX + ks * 32 + g * 8];

  f32x4 acc[8];
#pragma unroll
  for (int jt = 0; jt < 8; jt++) acc[jt] = (f32x4){0.f, 0.f, 0.f, 0.f};

#pragma unroll
  for (int ks = 0; ks < 4; ks++) {
#pragma unroll
    for (int jt = 0; jt < 8; jt++) {
      short8 bfr = *(const short8*)&wl[(jt * 16 + qr) * LPX + ks * 32 + g * 8];
      acc[jt] = MFMA16(af[ks], bfr, acc[jt]);
    }
  }

  float bbv[8];
#pragma unroll
  for (int jt = 0; jt < 8; jt++) bbv[jt] = bb[jt * 16 + qr];

  float ssq[4] = {0.f, 0.f, 0.f, 0.f};
#pragma unroll
  for (int jt = 0; jt < 8; jt++)
#pragma unroll
    for (int r = 0; r < 4; r++) {
      float yv = acc[jt][r] + bbv[jt];
      acc[jt][r] = yv;
      float s2 = yv * yv;
      if (jt == 0) s2 = (qr == 0) ? 0.f : s2;   // exclude d=0
      ssq[r] += s2;
    }
#pragma unroll
  for (int r = 0; r < 4; r++) {
    ssq[r] += __shfl_xor(ssq[r], 1);
    ssq[r] += __shfl_xor(ssq[r], 2);
    ssq[r] += __shfl_xor(ssq[r], 4);
    ssq[r] += __shfl_xor(ssq[r], 8);
  }

  const float es = __expf(ss[0]);
  const float fold = 2.0f / attn_scale[0];

  float tvv[4], sclv[4];
#pragma unroll
  for (int r = 0; r < 4; r++) {
    float y0 = __shfl(acc[0][r], l & 48);     // qr==0 lane of same g: d=0 value
    float tv = es / (1.0f + __expf(-y0)) + 1.1f;
    tvv[r] = tv;
    sclv[r] = sqrtf((tv * tv - 1.0f) / ssq[r]);
  }
  if (qr == 0) {
#pragma unroll
    for (int r = 0; r < 4; r++) {
      tml[r0 + g * 4 + r] = tvv[r];
      scl[r0 + g * 4 + r] = sclv[r];
    }
  }
#pragma unroll
  for (int jt = 0; jt < 8; jt++)
#pragma unroll
    for (int r = 0; r < 4; r++)
      yl[(r0 + g * 4 + r) * LPY + jt * 16 + qr] = acc[jt][r];
  __syncthreads();

  const long gbase = row0 * 128;
  if (z == 0) {
    for (int i = t; i < 64 * 128; i += 256) {
      int r = i >> 7, d = i & 127;
      float v = (d == 0) ? 0.f : yl[r * LPY + d] * scl[r] * fold;
      qout[gbase + i] = f2bf(v);
    }
    if (t < 64) tqo[row0 + t] = -tml[t] * fold;
  } else if (z == 1) {
    for (int i = t; i < 64 * 128; i += 256) {
      int r = i >> 7, d = i & 127;
      float v = (d == 0) ? 0.f : yl[r * LPY + d] * scl[r];
      kout[gbase + i] = f2bf(v);
    }
    if (t < 64) tko[row0 + t] = tml[t];
  } else {
    const int b = (int)(row0 >> 11);
    const int lpos = (int)(row0 & 2047);
    for (int i = t; i < 128 * 64; i += 256) {
      int d = i >> 6, r = i & 63;
      float v = (d == 0) ? tml[r] : yl[r * LPY + d] * scl[r];
      u16 hi = f2bf(v);
      float lo = v - bf2f(hi);
      long idx = ((long)(b * 128 + d)) * 2048 + lpos + r;
      vthi[idx] = hi;
      vtlo[idx] = f2bf(lo);
    }
    if (t < 128) {
      float s = 0.f;
      for (int r = 0; r < 64; r++)
        s += (t == 0) ? tml[r] : yl[r * LPY + t] * scl[r];
      int blk = (int)((row0 >> 6) & 31);
      vpart[((long)(b * 32 + blk)) * 128 + t] = s;
    }
  }
}

// ---------------- pack key-padding mask: one wave per 64-bit word -----------
__global__ __launch_bounds__(256) void pack_mask_kernel(
    const int* __restrict__ mask, u64* __restrict__ pmask)
{
  int gt = blockIdx.x * 256 + threadIdx.x;
  int w = gt >> 6;
  int lane = gt & 63;
  if (w >= Bsz * 32) return;
  u64 word = __ballot(mask[w * 64 + lane] != 0);
  if (lane == 0) pmask[w] = word;
}

// ---------------- deterministic v-sum reduce --------------------------------
__global__ __launch_bounds__(128) void vreduce_kernel(
    const float* __restrict__ vpart, float* __restrict__ vsum)
{
  int i = blockIdx.x * 128 + threadIdx.x;
  int b = i >> 7, d = i & 127;
  float s = 0.f;
  for (int j = 0; j < 32; j++) s += vpart[((long)(b * 32 + j)) * 128 + d];
  vsum[i] = s;
}

// ---------------- flash attention + Lorentz epilogue ------------------------
// FIXED-SHIFT softmax (no running max / rescale / stat exchange -> ONE
// barrier/tile). Block = 512 thr = 8 waves on a 32-q-row strip: wave w owns
// keys [16w,+16) and d in [16w,+16) -> K,V fully register-resident, prefetched
// one tile ahead; ONLY P goes through LDS (16KB dbuf, XOR-swizzle).
// __launch_bounds__(512, 2): 256-reg budget -- r6/r7/r8 precedent shows the
// compiler allocates ~124 VGPR spill-free here, and 124<=128 still lets HW
// co-schedule 2 blocks/CU (4 waves/SIMD). The (512,4) bound made the
// allocator squeeze to 64 and spill (r14: WRITE_SIZE 37MB). b = blk&7 (XCD).
__global__ __launch_bounds__(512, 2) void flash_kernel(
    const u16* __restrict__ qbf, const u16* __restrict__ kb,
    const u16* __restrict__ vthi, const u16* __restrict__ vtlo,
    const float* __restrict__ tq, const float* __restrict__ tk,
    const u64* __restrict__ pmask, const float* __restrict__ vsum,
    const float* __restrict__ sqp, const float* __restrict__ skp,
    const float* __restrict__ asp,
    float* __restrict__ out)
{
  __shared__ u16 Pl[2][32 * 128];       // 16 KB, XOR-swizzled (chunk ^= row&7)
  __shared__ float lLd[8][2][16];
  __shared__ float ssqw[8][2][16];

  const int t = threadIdx.x;
  const int w = t >> 6, l = t & 63;
  const int qr = l & 15, g = l >> 4;
  const int blk = blockIdx.x;
  const int b = blk & 7;                // batch == XCD (round-robin dispatch)
  const int s = 63 - (blk >> 3);        // 32-row strip, longest first
  const int qbase = s * 32;
  const int nkt = (qbase + 159) >> 7;   // 128-key tiles covering [0, qbase+32)

  // data-independent logit bound -> fixed softmax shift
  const float fold = 2.0f / asp[0];
  const float tqm = __expf(sqp[0]) + 1.1f;
  const float tkm = __expf(skp[0]) + 1.1f;
  const float MS = fold * sqrtf((tqm * tqm - 1.f) * (tkm * tkm - 1.f)) + 1.0f;

  short8 qf[2][4];
  float tqv0, tqv1;
  {
    const u16* qp0 = qbf + ((long)(b * 2048 + qbase + qr)) * 128 + g * 8;
    const u16* qp1 = qp0 + 16 * 128;
#pragma unroll
    for (int ks = 0; ks < 4; ks++) {
      qf[0][ks] = *(const short8*)(qp0 + ks * 32);
      qf[1][ks] = *(const short8*)(qp1 + ks * 32);
    }
    tqv0 = tq[b * 2048 + qbase + qr];
    tqv1 = tq[b * 2048 + qbase + 16 + qr];
  }

  const u16* kbase  = kb   + ((long)(b * 2048 + 16 * w + qr)) * 128 + g * 8;
  const u16* vhbase = vthi + ((long)(b * 128 + 16 * w + qr)) * 2048 + g * 8;
  const u16* vlbase = vtlo + ((long)(b * 128 + 16 * w + qr)) * 2048 + g * 8;

  float lsum0 = 0.f, lsum1 = 0.f;
  f32x4 acc0 = (f32x4){0.f, 0.f, 0.f, 0.f};
  f32x4 acc1 = (f32x4){0.f, 0.f, 0.f, 0.f};

  short8 kc[4], vh[4], vl[4];
#pragma unroll
  for (int ks = 0; ks < 4; ks++) kc[ks] = *(const short8*)(kbase + ks * 32);
  f32x4 tkvc = *(const f32x4*)(tk + b * 2048 + 16 * w + g * 4);
  u64 mwc = pmask[b * 32 + (w >> 2)];

  int cur = 0;
  for (int kt = 0; kt < nkt; kt++) {
    const long k0 = (long)kt << 7;

    // ---- QK(kt) from registers ----
    f32x4 sv0 = (f32x4){0.f, 0.f, 0.f, 0.f};
    f32x4 sv1 = (f32x4){0.f, 0.f, 0.f, 0.f};
#pragma unroll
    for (int ks = 0; ks < 4; ks++) {
      sv0 = MFMA16(kc[ks], qf[0][ks], sv0);
      sv1 = MFMA16(kc[ks], qf[1][ks], sv1);
    }
    // prefetch K(kt+1) into the same regs (rotation)
    if (kt + 1 < nkt) {
      const u16* kp = kbase + (k0 + 128) * 128;
#pragma unroll
      for (int ks = 0; ks < 4; ks++) kc[ks] = *(const short8*)(kp + ks * 32);
    }

    // ---- fixed-shift softmax (no max, no rescale) ----
    const bool bndry = (k0 + 127 > qbase);
    float p0[4], p1[4];
#pragma unroll
    for (int r = 0; r < 4; r++) {
      int kl = 16 * w + 4 * g + r;
      bool bad = ((mwc >> (kl & 63)) & 1ull) != 0ull;
      bool bad0 = bad, bad1 = bad;
      if (bndry) {
        bad0 |= (k0 + kl > qbase + qr);
        bad1 |= (k0 + kl > qbase + 16 + qr);
      }
      float e0 = __expf(sv0[r] + tqv0 * tkvc[r] - MS);
      float e1 = __expf(sv1[r] + tqv1 * tkvc[r] - MS);
      p0[r] = bad0 ? 0.f : e0;
      p1[r] = bad1 ? 0.f : e1;
      lsum0 += p0[r];
      lsum1 += p1[r];
    }
    // P -> LDS (swizzled)
    {
      int pch = ((2 * w + (g >> 1)) ^ (qr & 7)) * 8 + (g & 1) * 4;
      u64 w0 = (u64)f2bf(p0[0]) | ((u64)f2bf(p0[1]) << 16)
             | ((u64)f2bf(p0[2]) << 32) | ((u64)f2bf(p0[3]) << 48);
      u64 w1 = (u64)f2bf(p1[0]) | ((u64)f2bf(p1[1]) << 16)
             | ((u64)f2bf(p1[2]) << 32) | ((u64)f2bf(p1[3]) << 48);
      *(u64*)&Pl[cur][qr * 128 + pch] = w0;
      *(u64*)&Pl[cur][(16 + qr) * 128 + pch] = w1;
    }
    // prefetch tkv/mask for kt+1
    if (kt + 1 < nkt) {
      tkvc = *(const f32x4*)(tk + b * 2048 + k0 + 128 + 16 * w + g * 4);
      mwc = pmask[b * 32 + (int)(k0 >> 6) + 2 + (w >> 2)];
    }

    // ---- PV(kt-1): P from LDS (prev buffer), V from registers ----
    if (kt > 0) {
      const u16* Pb = &Pl[cur ^ 1][0];
#pragma unroll
      for (int ks = 0; ks < 4; ks++) {
        int ch = ((4 * ks + g) ^ (qr & 7)) * 8;
        short8 pf0 = *(const short8*)&Pb[qr * 128 + ch];
        short8 pf1 = *(const short8*)&Pb[(16 + qr) * 128 + ch];
        acc0 = MFMA16(vh[ks], pf0, acc0);
        acc0 = MFMA16(vl[ks], pf0, acc0);
        acc1 = MFMA16(vh[ks], pf1, acc1);
        acc1 = MFMA16(vl[ks], pf1, acc1);
      }
    }

    // ---- issue V(kt) loads (consumed next interval / final PV) ----
#pragma unroll
    for (int ks = 0; ks < 4; ks++) {
      vh[ks] = *(const short8*)(vhbase + k0 + ks * 32);
      vl[ks] = *(const short8*)(vlbase + k0 + ks * 32);
    }

    // single barrier: drain LDS writes only; global loads stay in flight
    asm volatile("s_waitcnt lgkmcnt(0)\n\ts_barrier" ::: "memory");
    cur ^= 1;
  }

  // ---- final PV(nkt-1) ----
  {
    const u16* Pb = &Pl[cur ^ 1][0];
#pragma unroll
    for (int ks = 0; ks < 4; ks++) {
      int ch = ((4 * ks + g) ^ (qr & 7)) * 8;
      short8 pf0 = *(const short8*)&Pb[qr * 128 + ch];
      short8 pf1 = *(const short8*)&Pb[(16 + qr) * 128 + ch];
      acc0 = MFMA16(vh[ks], pf0, acc0);
      acc0 = MFMA16(vl[ks], pf0, acc0);
      acc1 = MFMA16(vh[ks], pf1, acc1);
      acc1 = MFMA16(vl[ks], pf1, acc1);
    }
  }

  // ---- epilogue: lsum reduce (once, not per tile) + Lorentz normalize ----
  lsum0 += __shfl_xor(lsum0, 16); lsum0 += __shfl_xor(lsum0, 32);
  lsum1 += __shfl_xor(lsum1, 16); lsum1 += __shfl_xor(lsum1, 32);
  if (g == 0) { lLd[w][0][qr] = lsum0; lLd[w][1][qr] = lsum1; }
  __syncthreads();

  float Lt0 = 0.f, Lt1 = 0.f;
#pragma unroll
  for (int j = 0; j < 8; j++) { Lt0 += lLd[j][0][qr]; Lt1 += lLd[j][1][qr]; }
  const bool mrow0 = (Lt0 == 0.f);      // fully masked -> uniform over ALL keys
  const bool mrow1 = (Lt1 == 0.f);
  const float invL0 = mrow0 ? 0.f : 1.0f / Lt0;
  const float invL1 = mrow1 ? 0.f : 1.0f / Lt1;

  const float* vs = vsum + b * 128;
  float av0[4], av1[4];
  float pp0 = 0.f, pp1 = 0.f;
#pragma unroll
  for (int r = 0; r < 4; r++) {
    int d = 16 * w + 4 * g + r;
    float u = vs[d] * (1.0f / 2048.0f);
    float a0 = mrow0 ? u : acc0[r] * invL0;
    float a1 = mrow1 ? u : acc1[r] * invL1;
    av0[r] = a0; av1[r] = a1;
    float sgn = (d == 0) ? -1.f : 1.f;
    pp0 += sgn * a0 * a0;
    pp1 += sgn * a1 * a1;
  }
  pp0 += __shfl_xor(pp0, 16); pp0 += __shfl_xor(pp0, 32);
  pp1 += __shfl_xor(pp1, 16); pp1 += __shfl_xor(pp1, 32);
  if (g == 0) { ssqw[w][0][qr] = pp0; ssqw[w][1][qr] = pp1; }
  __syncthreads();

  float lor0 = 0.f, lor1 = 0.f;
#pragma unroll
  for (int j = 0; j < 8; j++) { lor0 += ssqw[j][0][qr]; lor1 += ssqw[j][1][qr]; }
  float rd0 = 1.0f / sqrtf(fmaxf(fabsf(lor0), 1e-8f));
  float rd1 = 1.0f / sqrtf(fmaxf(fabsf(lor1), 1e-8f));

  float* op0 = out + ((long)(b * 2048 + qbase + qr)) * 128 + 16 * w + 4 * g;
  float* op1 = out + ((long)(b * 2048 + qbase + 16 + qr)) * 128 + 16 * w + 4 * g;
  f32x4 o0, o1;
  o0[0] = av0[0] * rd0; o0[1] = av0[1] * rd0; o0[2] = av0[2] * rd0; o0[3] = av0[3] * rd0;
  o1[0] = av1[0] * rd1; o1[1] = av1[1] * rd1; o1[2] = av1[2] * rd1; o1[3] = av1[3] * rd1;
  *(f32x4*)op0 = o0;
  *(f32x4*)op1 = o1;
}

// ---------------- launch ----------------------------------------------------
extern "C" void kernel_launch(void* const* d_in, const int* in_sizes, int n_in,
                              void* d_out, int out_size, void* d_ws, size_t ws_size,
                              hipStream_t stream)
{
  const float* query = (const float*)d_in[0];
  const float* key   = (const float*)d_in[1];
  const float* value = (const float*)d_in[2];
  const int*   mask  = (const int*)d_in[3];
  const float* Wq = (const float*)d_in[4];
  const float* bq = (const float*)d_in[5];
  const float* sq = (const float*)d_in[6];
  const float* Wk = (const float*)d_in[7];
  const float* bk = (const float*)d_in[8];
  const float* sk = (const float*)d_in[9];
  const float* Wv = (const float*)d_in[10];
  const float* bv = (const float*)d_in[11];
  const float* sv = (const float*)d_in[12];
  const float* attn_scale = (const float*)d_in[13];
  // d_in[14] = attn_bias: cancels in softmax, unused

  float* out = (float*)d_out;
  char* ws = (char*)d_ws;

  float* vsum  = (float*)ws;                        // 4 KB
  u64*   pmask = (u64*)(ws + 4096);                 // 2 KB (pad to 4 KB)
  float* tqa   = (float*)(ws + 8192);               // 64 KB
  float* tka   = (float*)(ws + 8192 + 65536);       // 64 KB
  float* vpart = (float*)(ws + 8192 + 131072);      // 128 KB
  u16*   wb    = (u16*)(ws + 8192 + 262144);        // 96 KB (pad to 128 KB)
  char*  big   = ws + 8192 + 262144 + 131072;
  u16*   qbuf  = (u16*)big;                         // 4 MB
  u16*   kbuf  = qbuf + (size_t)16384 * 128;        // 4 MB
  u16*   vthi  = kbuf + (size_t)16384 * 128;        // 4 MB
  u16*   vtlo  = vthi + (size_t)16384 * 128;        // 4 MB

  wconv_kernel<<<192, 256, 0, stream>>>(Wq, Wk, Wv, wb);
  proj_kernel<<<dim3(256, 1, 3), 256, 0, stream>>>(
      query, key, value, wb, bq, bk, bv, sq, sk, sv, attn_scale,
      qbuf, kbuf, vthi, vtlo, tqa, tka, vpart);
  pack_mask_kernel<<<64, 256, 0, stream>>>(mask, pmask);
  vreduce_kernel<<<8, 128, 0, stream>>>(vpart, vsum);
  flash_kernel<<<512, 512, 0, stream>>>(
      qbuf, kbuf, vthi, vtlo, tqa, tka, pmask, vsum, sq, sk, attn_scale, out);
}